// Round 9
// baseline (553.150 us; speedup 1.0000x reference)
//
#include <hip/hip_runtime.h>
#include <hip/hip_bf16.h>

// Attn: energies = out_state @ (history @ W.T).T ; softmax rows.
// (bias dropped: os.b is constant per softmax row -> cancels in softmax.)
// S2=S1=4096, N=1024. fp32 in/out. bf16 hi/lo 3-term GEMM folded into K=3072.
// R7: 256x128 stage-2 tile (kept). R8: depth-2 vmcnt pipeline (neutral ->
// reverted to dbuf __syncthreads).
// R9: staged-bytes/slot is ~12 B/cyc/CU across ALL structures (R1-R8) ->
// the global_load_lds DMA commit path is the binding resource. Hybrid
// staging: A-slab via DMA (16 KB), B-slab via global->VGPR->ds_write_b128
// (8 KB) -- moves 1/3 of the bytes onto the VMEM-return + LDS-write ports.

typedef __bf16 bf16x8 __attribute__((ext_vector_type(8)));
typedef float f32x4 __attribute__((ext_vector_type(4)));
typedef unsigned short u16x4 __attribute__((ext_vector_type(4)));

__device__ __forceinline__ unsigned short f2bf(float x) {
  unsigned int u = __float_as_uint(x);
  u += 0x7fffu + ((u >> 16) & 1u);   // RNE
  return (unsigned short)(u >> 16);
}
__device__ __forceinline__ float bf2f(unsigned short h) {
  return __uint_as_float(((unsigned int)h) << 16);
}

__device__ __forceinline__ void async_copy_16(void* lds, const void* gsrc) {
  __builtin_amdgcn_global_load_lds(
      (const __attribute__((address_space(1))) void*)gsrc,
      (__attribute__((address_space(3))) void*)lds, 16, 0, 0);
}

// Split fp32 X[rows x 1024] -> Y[rows x 3072] bf16.
// bside=0 (A-operand): [hi | lo | hi]   bside=1 (B-operand): [hi | hi | lo]
__global__ __launch_bounds__(256)
void split_kernel(const float* __restrict__ X, unsigned short* __restrict__ Y, int bside) {
  const size_t row = blockIdx.x;
  const int c4 = threadIdx.x;                       // 256 threads x 4 cols = 1024
  float4 x = ((const float4*)(X + row * 1024))[c4];
  float xs[4] = {x.x, x.y, x.z, x.w};
  u16x4 h, l;
#pragma unroll
  for (int i = 0; i < 4; ++i) {
    unsigned short hh = f2bf(xs[i]);
    h[i] = hh;
    l[i] = f2bf(xs[i] - bf2f(hh));
  }
  u16x4* y0 = (u16x4*)(Y + row * 3072 + (size_t)c4 * 4);  // 256 u16x4 per 1024 cols
  if (bside) { y0[0] = h; y0[256] = h; y0[512] = l; }
  else       { y0[0] = h; y0[256] = l; y0[512] = h; }
}

// C[M,N] = A[M,K] . B[N,K]^T, bf16 in, fp32 acc. 256 threads, wave grid 2x2,
// wave tile (BM/2) x (BN/2). Fragment-ordered LDS: 16-row group g, k-seg s
// (8 bf16), row r at byte g*1024 + s*256 + r*16 == group base + lane*16
// (lane = s*16+r) -> matches global_load_lds wave-uniform-base+lane*16; 2-way
// bank aliasing only (free) on ds_read_b128 frag loads. The B-side reg-staging
// uses the SAME lane mapping (load *(uint4*)(row lr, kseg ls) -> ds_write_b128
// at lane*16), so layouts are identical either path.
// Hybrid dbuf iter: barrier (drains A-DMA issued last iter + B lgkm) ->
// [DMA A(k+1) -> buf^1; issue global_load B(k+1) -> regs] -> compute(buf) ->
// ds_write B(k+1) -> buf^1.
// EPI=0: store fp32 C. EPI=1: write [hi|hi|lo] split of acc into P2.
template <int BM, int BN, int EPI, int GM, int GN, int RM, int RN>
__global__ __launch_bounds__(256)
void gemm_bt(const unsigned short* __restrict__ A,
             const unsigned short* __restrict__ B,
             float* __restrict__ C,
             unsigned short* __restrict__ P2,
             int M, int N, int K) {
  constexpr int MT = BM / 32;            // m-frags per wave
  constexpr int NT = BN / 32;            // n-frags per wave
  constexpr int NA = BM / 64;            // A DMA chunks per wave
  constexpr int NB = BN / 64;            // B reg chunks per wave
  __shared__ unsigned short As[2][BM * 32];
  __shared__ unsigned short Bs[2][BN * 32];

  const int tid = threadIdx.x;
  const int w = tid >> 6;
  const int lane = tid & 63;
  const int wm = w >> 1, wn = w & 1;
  const int lr = lane & 15;              // m/n index within 16-tile
  const int ls = lane >> 4;              // k-segment (8 bf16 each)

  // XCD-aware super-tile swizzle
  const int id = blockIdx.x;
  const int xcd = id & 7;
  const int j = id >> 3;
  const int bm = ((xcd % (GM / RM)) * RM + (j % RM)) * BM;
  const int bn = ((xcd / (GM / RM)) * RN + (j / RM)) * BN;

  // A staging source pointers (DMA path)
  const unsigned short* pa[NA];
#pragma unroll
  for (int c = 0; c < NA; ++c)
    pa[c] = A + (size_t)(bm + (w * NA + c) * 16 + lr) * K + ls * 8;
  // B staging source pointers (reg path; same lane mapping as DMA)
  const unsigned short* pb[NB];
#pragma unroll
  for (int c = 0; c < NB; ++c)
    pb[c] = B + (size_t)(bn + (w * NB + c) * 16 + lr) * K + ls * 8;
  // B LDS write targets per buffer
  uint4* wb[2][NB];
#pragma unroll
  for (int u = 0; u < 2; ++u)
#pragma unroll
    for (int c = 0; c < NB; ++c)
      wb[u][c] = (uint4*)&Bs[u][(w * NB + c) * 512 + lane * 8];

  f32x4 acc[MT][NT] = {};

  // prologue: slab 0 -- A via DMA, B via regs
#pragma unroll
  for (int c = 0; c < NA; ++c)
    async_copy_16(&As[0][(w * NA + c) * 512], pa[c]);
  uint4 rb[NB];
#pragma unroll
  for (int c = 0; c < NB; ++c) rb[c] = *(const uint4*)pb[c];
#pragma unroll
  for (int c = 0; c < NB; ++c) *wb[0][c] = rb[c];

  int cur = 0;
  for (int kt = 0; kt < K; kt += 32) {
    __syncthreads();   // drains A-DMA (vmcnt) + B ds_writes (lgkm); publishes cur

    const bool more = kt + 32 < K;
    const int nxt = cur ^ 1;
    if (more) {
      // issue next A-slab DMA and next B-slab register loads up front
#pragma unroll
      for (int c = 0; c < NA; ++c)
        async_copy_16(&As[nxt][(w * NA + c) * 512], pa[c] + kt + 32);
#pragma unroll
      for (int c = 0; c < NB; ++c)
        rb[c] = *(const uint4*)(pb[c] + kt + 32);
    }

    bf16x8 af[MT], bfr[NT];
#pragma unroll
    for (int mt = 0; mt < MT; ++mt)
      af[mt] = *(const bf16x8*)&As[cur][(wm * MT + mt) * 512 + ls * 128 + lr * 8];
#pragma unroll
    for (int nt = 0; nt < NT; ++nt)
      bfr[nt] = *(const bf16x8*)&Bs[cur][(wn * NT + nt) * 512 + ls * 128 + lr * 8];

#pragma unroll
    for (int mt = 0; mt < MT; ++mt)
#pragma unroll
      for (int nt = 0; nt < NT; ++nt)
        acc[mt][nt] = __builtin_amdgcn_mfma_f32_16x16x32_bf16(af[mt], bfr[nt], acc[mt][nt], 0, 0, 0);

    if (more) {
      // dep-driven vmcnt wait lands here, after the compute phase
#pragma unroll
      for (int c = 0; c < NB; ++c) *wb[nxt][c] = rb[c];
    }
    cur ^= 1;
  }

  // Epilogue. C/D layout (m89/m91): col(n) = lane&15, row(m) = (lane>>4)*4 + reg.
  const int cm0 = bm + wm * (BM / 2);
  const int cn0 = bn + wn * (BN / 2);
#pragma unroll
  for (int mt = 0; mt < MT; ++mt) {
#pragma unroll
    for (int nt = 0; nt < NT; ++nt) {
      const int col = cn0 + nt * 16 + lr;
      const int row0 = cm0 + mt * 16 + ls * 4;
      if constexpr (EPI == 0) {
#pragma unroll
        for (int r = 0; r < 4; ++r)
          C[(size_t)(row0 + r) * N + col] = acc[mt][nt][r];
      } else {
#pragma unroll
        for (int r = 0; r < 4; ++r) {
          const float p = acc[mt][nt][r];
          const unsigned short h = f2bf(p);
          const unsigned short l = f2bf(p - bf2f(h));
          const size_t base = (size_t)(row0 + r) * 3072 + col;
          P2[base] = h;
          P2[base + 1024] = h;
          P2[base + 2048] = l;
        }
      }
    }
  }
}

// In-place row softmax, N=4096, one block per row, 16 floats/thread in regs.
__global__ __launch_bounds__(256)
void softmax_inplace(float* __restrict__ C, int N) {
  float4* r4 = (float4*)(C + (size_t)blockIdx.x * N);
  const int t = threadIdx.x;
  float4 v[4];
  float mx = -3.0e38f;
#pragma unroll
  for (int i = 0; i < 4; ++i) {
    v[i] = r4[t + i * 256];
    mx = fmaxf(mx, fmaxf(fmaxf(v[i].x, v[i].y), fmaxf(v[i].z, v[i].w)));
  }
#pragma unroll
  for (int o = 32; o; o >>= 1) mx = fmaxf(mx, __shfl_xor(mx, o, 64));
  __shared__ float smax[4], ssum[4];
  const int w = t >> 6;
  if ((t & 63) == 0) smax[w] = mx;
  __syncthreads();
  mx = fmaxf(fmaxf(smax[0], smax[1]), fmaxf(smax[2], smax[3]));
  float s = 0.f;
#pragma unroll
  for (int i = 0; i < 4; ++i) {
    v[i].x = __expf(v[i].x - mx);
    v[i].y = __expf(v[i].y - mx);
    v[i].z = __expf(v[i].z - mx);
    v[i].w = __expf(v[i].w - mx);
    s += (v[i].x + v[i].y) + (v[i].z + v[i].w);
  }
#pragma unroll
  for (int o = 32; o; o >>= 1) s += __shfl_xor(s, o, 64);
  if ((t & 63) == 0) ssum[w] = s;
  __syncthreads();
  const float inv = 1.0f / (ssum[0] + ssum[1] + ssum[2] + ssum[3]);
#pragma unroll
  for (int i = 0; i < 4; ++i) {
    v[i].x *= inv; v[i].y *= inv; v[i].z *= inv; v[i].w *= inv;
    r4[t + i * 256] = v[i];
  }
}

extern "C" void kernel_launch(void* const* d_in, const int* in_sizes, int n_in,
                              void* d_out, int out_size, void* d_ws, size_t ws_size,
                              hipStream_t stream) {
  const float* out_state = (const float*)d_in[0];  // [4096,1024]
  const float* history   = (const float*)d_in[1];  // [4096,1024]
  const float* W         = (const float*)d_in[2];  // [1024,1024]
  float* out = (float*)d_out;                      // [4096,4096]

  unsigned short* H2 = (unsigned short*)d_ws;                 // 4096x3072
  unsigned short* W2 = H2 + (size_t)4096 * 3072;              // 1024x3072
  unsigned short* A2 = W2 + (size_t)1024 * 3072;              // 4096x3072
  unsigned short* P2 = A2 + (size_t)4096 * 3072;              // 4096x3072

  split_kernel<<<4096, 256, 0, stream>>>(history, H2, 0);
  split_kernel<<<1024, 256, 0, stream>>>(W, W2, 1);
  split_kernel<<<4096, 256, 0, stream>>>(out_state, A2, 0);

  // proj -> P2 split. BM=128, BN=64: 32x16 tiles -> 512 blocks.
  gemm_bt<128, 64, 1, 32, 16, 8, 8><<<512, 256, 0, stream>>>(
      H2, W2, nullptr, P2, 4096, 1024, 3072);

  // energies -> d_out. BM=256, BN=128: 16x32 tiles -> 512 blocks.
  gemm_bt<256, 128, 0, 16, 32, 8, 8><<<512, 256, 0, stream>>>(
      A2, P2, out, nullptr, 4096, 4096, 3072);

  softmax_inplace<<<4096, 256, 0, stream>>>(out, 4096);
}

// Round 10
// 332.689 us; speedup vs baseline: 1.6627x; 1.6627x over previous
//
#include <hip/hip_runtime.h>
#include <hip/hip_bf16.h>

// Attn: energies = out_state @ (history @ W.T).T ; softmax rows.
// (bias dropped: os.b is constant per softmax row -> cancels in softmax.)
// S2=S1=4096, N=1024. fp32 in/out. bf16 hi/lo 3-term GEMM folded into K=3072.
// R7 (kept): 256x128 stage-2 tile, dbuf global_load_lds, 161 us @ MfmaUtil 27%.
// R9 (reverted): hybrid reg-staging -> VGPR 168, 1 block/CU, 378 us.
// R10: slot audit -- stage-1 and stage-2 share a ~2000-cyc barrier slot
// regardless of staged bytes (12 vs 24 KB), so slot COUNT is the lever.
// Stage-1 gets BK=64 (KU=2 sub-slabs per barrier): 48 slots instead of 96,
// LDS 48 KB dbuf -> still 3 blocks/CU. Stage-2 unchanged (KU=1).

typedef __bf16 bf16x8 __attribute__((ext_vector_type(8)));
typedef float f32x4 __attribute__((ext_vector_type(4)));
typedef unsigned short u16x4 __attribute__((ext_vector_type(4)));

__device__ __forceinline__ unsigned short f2bf(float x) {
  unsigned int u = __float_as_uint(x);
  u += 0x7fffu + ((u >> 16) & 1u);   // RNE
  return (unsigned short)(u >> 16);
}
__device__ __forceinline__ float bf2f(unsigned short h) {
  return __uint_as_float(((unsigned int)h) << 16);
}

__device__ __forceinline__ void async_copy_16(void* lds, const void* gsrc) {
  __builtin_amdgcn_global_load_lds(
      (const __attribute__((address_space(1))) void*)gsrc,
      (__attribute__((address_space(3))) void*)lds, 16, 0, 0);
}

// Split fp32 X[rows x 1024] -> Y[rows x 3072] bf16.
// bside=0 (A-operand): [hi | lo | hi]   bside=1 (B-operand): [hi | hi | lo]
__global__ __launch_bounds__(256)
void split_kernel(const float* __restrict__ X, unsigned short* __restrict__ Y, int bside) {
  const size_t row = blockIdx.x;
  const int c4 = threadIdx.x;                       // 256 threads x 4 cols = 1024
  float4 x = ((const float4*)(X + row * 1024))[c4];
  float xs[4] = {x.x, x.y, x.z, x.w};
  u16x4 h, l;
#pragma unroll
  for (int i = 0; i < 4; ++i) {
    unsigned short hh = f2bf(xs[i]);
    h[i] = hh;
    l[i] = f2bf(xs[i] - bf2f(hh));
  }
  u16x4* y0 = (u16x4*)(Y + row * 3072 + (size_t)c4 * 4);  // 256 u16x4 per 1024 cols
  if (bside) { y0[0] = h; y0[256] = h; y0[512] = l; }
  else       { y0[0] = h; y0[256] = l; y0[512] = h; }
}

// C[M,N] = A[M,K] . B[N,K]^T, bf16 in, fp32 acc. 256 threads, wave grid 2x2,
// wave tile (BM/2) x (BN/2). Fragment-ordered LDS per 32-k sub-slab: 16-row
// group g, k-seg s (8 bf16), row r at byte g*1024 + s*256 + r*16 == group
// base + lane*16 (lane = s*16+r) -> matches global_load_lds wave-uniform-
// base+lane*16; 2-way bank aliasing only (free) on ds_read_b128 frag loads.
// KU sub-slabs are staged per barrier (BK = 32*KU): iter = barrier (drains
// prev prefetch DMAs, publishes buf cur) -> issue DMAs for next BK-slab into
// buf^1 -> KU x (frag reads + MFMA) on buf cur.
// EPI=0: store fp32 C. EPI=1: write [hi|hi|lo] split of acc into P2.
template <int BM, int BN, int KU, int EPI, int GM, int GN, int RM, int RN>
__global__ __launch_bounds__(256)
void gemm_bt(const unsigned short* __restrict__ A,
             const unsigned short* __restrict__ B,
             float* __restrict__ C,
             unsigned short* __restrict__ P2,
             int M, int N, int K) {
  constexpr int MT = BM / 32;            // m-frags per wave
  constexpr int NT = BN / 32;            // n-frags per wave
  constexpr int NA = BM / 64;            // A DMA chunks per wave per sub-slab
  constexpr int NB = BN / 64;            // B DMA chunks per wave per sub-slab
  __shared__ unsigned short As[2][KU * BM * 32];
  __shared__ unsigned short Bs[2][KU * BN * 32];

  const int tid = threadIdx.x;
  const int w = tid >> 6;
  const int lane = tid & 63;
  const int wm = w >> 1, wn = w & 1;
  const int lr = lane & 15;              // m/n index within 16-tile
  const int ls = lane >> 4;              // k-segment (8 bf16 each)

  // XCD-aware super-tile swizzle
  const int id = blockIdx.x;
  const int xcd = id & 7;
  const int j = id >> 3;
  const int bm = ((xcd % (GM / RM)) * RM + (j % RM)) * BM;
  const int bn = ((xcd / (GM / RM)) * RN + (j / RM)) * BN;

  // staging source pointers (hoisted; advance by k-offset each issue)
  const unsigned short* pa[NA];
#pragma unroll
  for (int c = 0; c < NA; ++c)
    pa[c] = A + (size_t)(bm + (w * NA + c) * 16 + lr) * K + ls * 8;
  const unsigned short* pb[NB];
#pragma unroll
  for (int c = 0; c < NB; ++c)
    pb[c] = B + (size_t)(bn + (w * NB + c) * 16 + lr) * K + ls * 8;

  f32x4 acc[MT][NT] = {};

  // stage one BK-slab (KU sub-slabs) starting at k-offset kt into buffer buf
  auto stage = [&](int buf, int kt) {
#pragma unroll
    for (int u = 0; u < KU; ++u) {
#pragma unroll
      for (int c = 0; c < NA; ++c)
        async_copy_16(&As[buf][u * BM * 32 + (w * NA + c) * 512], pa[c] + kt + u * 32);
#pragma unroll
      for (int c = 0; c < NB; ++c)
        async_copy_16(&Bs[buf][u * BN * 32 + (w * NB + c) * 512], pb[c] + kt + u * 32);
    }
  };

  auto compute = [&](int buf) {
#pragma unroll
    for (int u = 0; u < KU; ++u) {
      bf16x8 af[MT], bfr[NT];
#pragma unroll
      for (int mt = 0; mt < MT; ++mt)
        af[mt] = *(const bf16x8*)&As[buf][u * BM * 32 + (wm * MT + mt) * 512 + ls * 128 + lr * 8];
#pragma unroll
      for (int nt = 0; nt < NT; ++nt)
        bfr[nt] = *(const bf16x8*)&Bs[buf][u * BN * 32 + (wn * NT + nt) * 512 + ls * 128 + lr * 8];
#pragma unroll
      for (int mt = 0; mt < MT; ++mt)
#pragma unroll
        for (int nt = 0; nt < NT; ++nt)
          acc[mt][nt] = __builtin_amdgcn_mfma_f32_16x16x32_bf16(af[mt], bfr[nt], acc[mt][nt], 0, 0, 0);
    }
  };

  // prologue: stage slab 0 into buf 0
  stage(0, 0);

  int cur = 0;
  for (int kt = 0; kt < K; kt += 32 * KU) {
    __syncthreads();   // drains our DMAs (vmcnt 0) + publishes buf `cur`
    if (kt + 32 * KU < K)
      stage(cur ^ 1, kt + 32 * KU);   // prefetch next BK-slab
    compute(cur);
    cur ^= 1;
  }

  // Epilogue. C/D layout (m89/m91): col(n) = lane&15, row(m) = (lane>>4)*4 + reg.
  const int cm0 = bm + wm * (BM / 2);
  const int cn0 = bn + wn * (BN / 2);
#pragma unroll
  for (int mt = 0; mt < MT; ++mt) {
#pragma unroll
    for (int nt = 0; nt < NT; ++nt) {
      const int col = cn0 + nt * 16 + lr;
      const int row0 = cm0 + mt * 16 + ls * 4;
      if constexpr (EPI == 0) {
#pragma unroll
        for (int r = 0; r < 4; ++r)
          C[(size_t)(row0 + r) * N + col] = acc[mt][nt][r];
      } else {
#pragma unroll
        for (int r = 0; r < 4; ++r) {
          const float p = acc[mt][nt][r];
          const unsigned short h = f2bf(p);
          const unsigned short l = f2bf(p - bf2f(h));
          const size_t base = (size_t)(row0 + r) * 3072 + col;
          P2[base] = h;
          P2[base + 1024] = h;
          P2[base + 2048] = l;
        }
      }
    }
  }
}

// In-place row softmax, N=4096, one block per row, 16 floats/thread in regs.
__global__ __launch_bounds__(256)
void softmax_inplace(float* __restrict__ C, int N) {
  float4* r4 = (float4*)(C + (size_t)blockIdx.x * N);
  const int t = threadIdx.x;
  float4 v[4];
  float mx = -3.0e38f;
#pragma unroll
  for (int i = 0; i < 4; ++i) {
    v[i] = r4[t + i * 256];
    mx = fmaxf(mx, fmaxf(fmaxf(v[i].x, v[i].y), fmaxf(v[i].z, v[i].w)));
  }
#pragma unroll
  for (int o = 32; o; o >>= 1) mx = fmaxf(mx, __shfl_xor(mx, o, 64));
  __shared__ float smax[4], ssum[4];
  const int w = t >> 6;
  if ((t & 63) == 0) smax[w] = mx;
  __syncthreads();
  mx = fmaxf(fmaxf(smax[0], smax[1]), fmaxf(smax[2], smax[3]));
  float s = 0.f;
#pragma unroll
  for (int i = 0; i < 4; ++i) {
    v[i].x = __expf(v[i].x - mx);
    v[i].y = __expf(v[i].y - mx);
    v[i].z = __expf(v[i].z - mx);
    v[i].w = __expf(v[i].w - mx);
    s += (v[i].x + v[i].y) + (v[i].z + v[i].w);
  }
#pragma unroll
  for (int o = 32; o; o >>= 1) s += __shfl_xor(s, o, 64);
  if ((t & 63) == 0) ssum[w] = s;
  __syncthreads();
  const float inv = 1.0f / (ssum[0] + ssum[1] + ssum[2] + ssum[3]);
#pragma unroll
  for (int i = 0; i < 4; ++i) {
    v[i].x *= inv; v[i].y *= inv; v[i].z *= inv; v[i].w *= inv;
    r4[t + i * 256] = v[i];
  }
}

extern "C" void kernel_launch(void* const* d_in, const int* in_sizes, int n_in,
                              void* d_out, int out_size, void* d_ws, size_t ws_size,
                              hipStream_t stream) {
  const float* out_state = (const float*)d_in[0];  // [4096,1024]
  const float* history   = (const float*)d_in[1];  // [4096,1024]
  const float* W         = (const float*)d_in[2];  // [1024,1024]
  float* out = (float*)d_out;                      // [4096,4096]

  unsigned short* H2 = (unsigned short*)d_ws;                 // 4096x3072
  unsigned short* W2 = H2 + (size_t)4096 * 3072;              // 1024x3072
  unsigned short* A2 = W2 + (size_t)1024 * 3072;              // 4096x3072
  unsigned short* P2 = A2 + (size_t)4096 * 3072;              // 4096x3072

  split_kernel<<<4096, 256, 0, stream>>>(history, H2, 0);
  split_kernel<<<1024, 256, 0, stream>>>(W, W2, 1);
  split_kernel<<<4096, 256, 0, stream>>>(out_state, A2, 0);

  // proj -> P2 split. BM=128, BN=64, KU=2 (BK=64): 48 barrier slots,
  // LDS 48 KB -> 3 blocks/CU. 512 blocks.
  gemm_bt<128, 64, 2, 1, 32, 16, 8, 8><<<512, 256, 0, stream>>>(
      H2, W2, nullptr, P2, 4096, 1024, 3072);

  // energies -> d_out. BM=256, BN=128, KU=1: identical to R7 best. 512 blocks.
  gemm_bt<256, 128, 1, 0, 16, 32, 8, 8><<<512, 256, 0, stream>>>(
      A2, P2, out, nullptr, 4096, 4096, 3072);

  softmax_inplace<<<4096, 256, 0, stream>>>(out, 4096);
}